// Round 14
// baseline (1117.589 us; speedup 1.0000x reference)
//
#include <hip/hip_runtime.h>
#include <math.h>

#define N_PTS 6000
#define DIM   1024
#define KSEL  300
#define GG    16
#define DGR   64
#define WSTR  6016   // padded row stride for logits W (6000 -> 6016)
#define XSTR  2048   // X = [hi|lo] f16 2-way split, row stride

typedef _Float16 half8 __attribute__((ext_vector_type(8)));
typedef float floatx4 __attribute__((ext_vector_type(4)));

__device__ __forceinline__ unsigned short f2h(float x) {
    _Float16 h = (_Float16)x;                   // v_cvt_f16_f32, RNE
    return __builtin_bit_cast(unsigned short, h);
}
__device__ __forceinline__ float h2f(unsigned short u) {
    return (float)__builtin_bit_cast(_Float16, u);
}

__device__ __forceinline__ void async_copy16(const void* gsrc, void* ldst) {
    __builtin_amdgcn_global_load_lds(
        (const __attribute__((address_space(1))) void*)gsrc,
        (__attribute__((address_space(3))) void*)ldst,
        16, 0, 0);
}

// ---------------------------------------------------------------------------
// MFMA f16 GEMM, NT: C[i][j] = scale * sum_k A[i,k]*B[j,k] (+bias[j])
// 128x128 tile, BK=32, 256 threads. Batched over z (az/bz double as split-K
// offsets for out_t). gidx != nullptr: A rows gathered as A[gidx[row]] (q).
// OF16: store output as f16.
// ---------------------------------------------------------------------------
template<bool OF16>
__global__ __launch_bounds__(256)
void mfma_gemm(const void* Av, long lda, long az,
               const void* Bv, long ldb, long bz,
               void* Cv, long ldc, long cz,
               int M, int N, int Kd,
               const float* __restrict__ bias, long biasz, float scale,
               const int* __restrict__ gidx)
{
    __shared__ unsigned short As[128 * 32];
    __shared__ unsigned short Bs[128 * 32];
    const int t = threadIdx.x;
    const int w = t >> 6, l = t & 63;
    const int wr = w >> 1, wc = w & 1;
    const int row0 = blockIdx.y * 128, col0 = blockIdx.x * 128;
    const int z = blockIdx.z;
    const unsigned short* Ab = (const unsigned short*)Av + (long)z * az;
    const unsigned short* Bb = (const unsigned short*)Bv + (long)z * bz;

    floatx4 acc[4][4];
#pragma unroll
    for (int i = 0; i < 4; i++)
#pragma unroll
        for (int j = 0; j < 4; j++) acc[i][j] = (floatx4){0.f, 0.f, 0.f, 0.f};

    int ra0 = row0 + (w * 2 + 0) * 16 + (l >> 2); ra0 = ra0 < M ? ra0 : M - 1;
    int ra1 = row0 + (w * 2 + 1) * 16 + (l >> 2); ra1 = ra1 < M ? ra1 : M - 1;
    int rb0 = col0 + (w * 2 + 0) * 16 + (l >> 2); rb0 = rb0 < N ? rb0 : N - 1;
    int rb1 = col0 + (w * 2 + 1) * 16 + (l >> 2); rb1 = rb1 < N ? rb1 : N - 1;
    const long rowA0 = gidx ? (long)gidx[ra0] : (long)ra0;
    const long rowA1 = gidx ? (long)gidx[ra1] : (long)ra1;
    const long lane_off = (l & 3) * 8;
    const unsigned short* gA0 = Ab + rowA0 * lda + lane_off;
    const unsigned short* gA1 = Ab + rowA1 * lda + lane_off;
    const unsigned short* gB0 = Bb + (long)rb0 * ldb + lane_off;
    const unsigned short* gB1 = Bb + (long)rb1 * ldb + lane_off;
    unsigned short* lA0 = As + ((w * 2 + 0) * 16) * 32;
    unsigned short* lA1 = As + ((w * 2 + 1) * 16) * 32;
    unsigned short* lB0 = Bs + ((w * 2 + 0) * 16) * 32;
    unsigned short* lB1 = Bs + ((w * 2 + 1) * 16) * 32;

#pragma unroll 1
    for (int k0 = 0; k0 < Kd; k0 += 32) {
        async_copy16(gA0 + k0, (void*)lA0);
        async_copy16(gA1 + k0, (void*)lA1);
        async_copy16(gB0 + k0, (void*)lB0);
        async_copy16(gB1 + k0, (void*)lB1);
        __syncthreads();
        half8 af[4], bfr[4];
#pragma unroll
        for (int ti = 0; ti < 4; ti++)
            af[ti] = *(const half8*)(As + (wr * 64 + ti * 16 + (l & 15)) * 32 + (l >> 4) * 8);
#pragma unroll
        for (int tj = 0; tj < 4; tj++)
            bfr[tj] = *(const half8*)(Bs + (wc * 64 + tj * 16 + (l & 15)) * 32 + (l >> 4) * 8);
#pragma unroll
        for (int ti = 0; ti < 4; ti++)
#pragma unroll
            for (int tj = 0; tj < 4; tj++)
                acc[ti][tj] = __builtin_amdgcn_mfma_f32_16x16x32_f16(
                    af[ti], bfr[tj], acc[ti][tj], 0, 0, 0);
        __syncthreads();
    }

    float* Cf = (float*)Cv + (long)z * cz;
    unsigned short* Ch = (unsigned short*)Cv + (long)z * cz;
    const float* bias_p = bias ? bias + (long)z * biasz : nullptr;
#pragma unroll
    for (int ti = 0; ti < 4; ti++) {
#pragma unroll
        for (int tj = 0; tj < 4; tj++) {
            const int c = col0 + wc * 64 + tj * 16 + (l & 15);
            const int rb = row0 + wr * 64 + ti * 16 + (l >> 4) * 4;
#pragma unroll
            for (int reg = 0; reg < 4; reg++) {
                int r = rb + reg;
                if (r >= M || c >= N) continue;
                float v = acc[ti][tj][reg] * scale;
                if (bias_p) v += bias_p[c];
                if (OF16) Ch[(long)r * ldc + c] = f2h(v);
                else      Cf[(long)r * ldc + c] = v;
            }
        }
    }
}

// ---------------------------------------------------------------------------
// GRAM kernel, fused-K: stage Ahi/Alo/Bhi/Blo ONCE per 32-k chunk (32 KB LDS),
// 3 MFMA combos (hi.hi, hi.lo, lo.hi) per barrier. Triangular grid, 1/cdist
// epilogue + mirrored store. (R13, measured-good)
// ---------------------------------------------------------------------------
__global__ __launch_bounds__(256)
void gram_kernel(const unsigned short* __restrict__ X,
                 float* __restrict__ C, const float* __restrict__ sqn, int nbm)
{
    __shared__ unsigned short Ah[128 * 32], Al[128 * 32];
    __shared__ unsigned short Bh[128 * 32], Bl[128 * 32];
    const int t = threadIdx.x;
    const int w = t >> 6, l = t & 63;
    const int wr = w >> 1, wc = w & 1;

    int tt = blockIdx.x, rem = nbm, bi = 0;
    while (tt >= rem) { tt -= rem; bi++; rem--; }
    const int bj = bi + tt;
    const int row0 = bi * 128, col0 = bj * 128;

    floatx4 acc[4][4];
#pragma unroll
    for (int i = 0; i < 4; i++)
#pragma unroll
        for (int j = 0; j < 4; j++) acc[i][j] = (floatx4){0.f, 0.f, 0.f, 0.f};

    int ra0 = row0 + (w * 2 + 0) * 16 + (l >> 2); ra0 = ra0 < N_PTS ? ra0 : N_PTS - 1;
    int ra1 = row0 + (w * 2 + 1) * 16 + (l >> 2); ra1 = ra1 < N_PTS ? ra1 : N_PTS - 1;
    int rb0 = col0 + (w * 2 + 0) * 16 + (l >> 2); rb0 = rb0 < N_PTS ? rb0 : N_PTS - 1;
    int rb1 = col0 + (w * 2 + 1) * 16 + (l >> 2); rb1 = rb1 < N_PTS ? rb1 : N_PTS - 1;
    const long lane_off = (l & 3) * 8;
    const unsigned short* gA0 = X + (long)ra0 * XSTR + lane_off;
    const unsigned short* gA1 = X + (long)ra1 * XSTR + lane_off;
    const unsigned short* gB0 = X + (long)rb0 * XSTR + lane_off;
    const unsigned short* gB1 = X + (long)rb1 * XSTR + lane_off;
    const long ldsoff0 = ((w * 2 + 0) * 16) * 32;
    const long ldsoff1 = ((w * 2 + 1) * 16) * 32;

#pragma unroll 1
    for (int k0 = 0; k0 < 1024; k0 += 32) {
        async_copy16(gA0 + k0, (void*)(Ah + ldsoff0));
        async_copy16(gA1 + k0, (void*)(Ah + ldsoff1));
        async_copy16(gA0 + k0 + 1024, (void*)(Al + ldsoff0));
        async_copy16(gA1 + k0 + 1024, (void*)(Al + ldsoff1));
        async_copy16(gB0 + k0, (void*)(Bh + ldsoff0));
        async_copy16(gB1 + k0, (void*)(Bh + ldsoff1));
        async_copy16(gB0 + k0 + 1024, (void*)(Bl + ldsoff0));
        async_copy16(gB1 + k0 + 1024, (void*)(Bl + ldsoff1));
        __syncthreads();

        const long aidx = (wr * 64 + (l & 15)) * 32 + (l >> 4) * 8;
        const long bidx = (wc * 64 + (l & 15)) * 32 + (l >> 4) * 8;
        half8 af[4], bfr[4];
#pragma unroll
        for (int ti = 0; ti < 4; ti++) af[ti] = *(const half8*)(Ah + aidx + ti * 16 * 32);
#pragma unroll
        for (int tj = 0; tj < 4; tj++) bfr[tj] = *(const half8*)(Bh + bidx + tj * 16 * 32);
#pragma unroll
        for (int ti = 0; ti < 4; ti++)
#pragma unroll
            for (int tj = 0; tj < 4; tj++)
                acc[ti][tj] = __builtin_amdgcn_mfma_f32_16x16x32_f16(
                    af[ti], bfr[tj], acc[ti][tj], 0, 0, 0);
#pragma unroll
        for (int tj = 0; tj < 4; tj++) bfr[tj] = *(const half8*)(Bl + bidx + tj * 16 * 32);
#pragma unroll
        for (int ti = 0; ti < 4; ti++)
#pragma unroll
            for (int tj = 0; tj < 4; tj++)
                acc[ti][tj] = __builtin_amdgcn_mfma_f32_16x16x32_f16(
                    af[ti], bfr[tj], acc[ti][tj], 0, 0, 0);
#pragma unroll
        for (int ti = 0; ti < 4; ti++) af[ti] = *(const half8*)(Al + aidx + ti * 16 * 32);
#pragma unroll
        for (int tj = 0; tj < 4; tj++) bfr[tj] = *(const half8*)(Bh + bidx + tj * 16 * 32);
#pragma unroll
        for (int ti = 0; ti < 4; ti++)
#pragma unroll
            for (int tj = 0; tj < 4; tj++)
                acc[ti][tj] = __builtin_amdgcn_mfma_f32_16x16x32_f16(
                    af[ti], bfr[tj], acc[ti][tj], 0, 0, 0);
        __syncthreads();
    }

#pragma unroll
    for (int ti = 0; ti < 4; ti++) {
#pragma unroll
        for (int tj = 0; tj < 4; tj++) {
            const int c = col0 + wc * 64 + tj * 16 + (l & 15);
            const int rb = row0 + wr * 64 + ti * 16 + (l >> 4) * 4;
            float rec4[4];
#pragma unroll
            for (int reg = 0; reg < 4; reg++) {
                int r = rb + reg;
                if (r >= N_PTS || c >= N_PTS) { rec4[reg] = 0.f; continue; }
                if (r == c) { rec4[reg] = INFINITY; }
                else {
                    float sq = sqn[r] + sqn[c] - 2.f * acc[ti][tj][reg];
                    rec4[reg] = 1.0f / sqrtf(fmaxf(sq, 0.f));
                }
                C[(long)r * N_PTS + c] = rec4[reg];
            }
            if (bi != bj && c < N_PTS && rb + 3 < N_PTS) {
                *(float4*)(C + (long)c * N_PTS + rb) =
                    make_float4(rec4[0], rec4[1], rec4[2], rec4[3]);
            }
        }
    }
}

// ---------------------------------------------------------------------------
// FAT KERNEL: block 0 = greedy FPS; blocks 1..96 = kk GEMM (R12 measured-good).
// FPS reduction (R14): butterfly shfl_xor -> 16 wave-mins in double-buffered
// LDS -> ONE barrier -> all threads reduce 16 keys in registers. Winner is the
// exact u64 min (topology-independent) -> selections identical to R7/R13.
// Loads: R7 float4 path (measured-good), unchanged.
// ---------------------------------------------------------------------------
#define FPS_T 1024

__global__ __launch_bounds__(1024)
void fps_kk_kernel(const float* __restrict__ Drec, int* __restrict__ idxout,
                   const unsigned short* __restrict__ X,
                   const unsigned short* __restrict__ Wk_h,
                   const float* __restrict__ bk,
                   unsigned short* __restrict__ kk_h)
{
    __shared__ __align__(16) unsigned long long red2[2][16];
    __shared__ unsigned short As[4][128 * 32];
    __shared__ unsigned short Bs[128 * 32];
    const int t = threadIdx.x;

    if (blockIdx.x == 0) {
        const bool act = t < 750;
        float ds[8];
        if (act) {
            const float4* p = (const float4*)Drec + 2 * t;
            float4 a0 = p[0], a1 = p[1];
            ds[0] = a0.x; ds[1] = a0.y; ds[2] = a0.z; ds[3] = a0.w;
            ds[4] = a1.x; ds[5] = a1.y; ds[6] = a1.z; ds[7] = a1.w;
        } else {
#pragma unroll
            for (int j = 0; j < 8; j++) ds[j] = INFINITY;
        }
        if (t == 0) idxout[0] = 0;

        for (int it = 1; it < KSEL; it++) {
            const int buf = it & 1;
            // local argmin (ascending j -> lowest n wins ties)
            float mv = ds[0]; int mi = 8 * t;
#pragma unroll
            for (int j = 1; j < 8; j++) {
                if (ds[j] < mv) { mv = ds[j]; mi = 8 * t + j; }
            }
            unsigned long long key = act
                ? (((unsigned long long)__float_as_uint(mv) << 32) | (unsigned)mi)
                : ~0ull;
            // wave butterfly: all 64 lanes end with the wave min
#pragma unroll
            for (int o = 1; o < 64; o <<= 1) {
                unsigned long long other = __shfl_xor(key, o);
                key = (other < key) ? other : key;
            }
            if ((t & 63) == 0) red2[buf][t >> 6] = key;
            __syncthreads();
            // every thread finishes in registers (broadcast reads, no conflicts)
            unsigned long long best = red2[buf][0];
#pragma unroll
            for (int i = 1; i < 16; i++) {
                unsigned long long other = red2[buf][i];
                best = (other < best) ? other : best;
            }
            const int sel = (int)(unsigned)best;
            if (t == 0) idxout[it] = sel;
            if (act) {
                const float4* rp = (const float4*)(Drec + (long)sel * N_PTS) + 2 * t;
                float4 r0 = rp[0], r1 = rp[1];
                ds[0] += r0.x; ds[1] += r0.y; ds[2] += r0.z; ds[3] += r0.w;
                ds[4] += r1.x; ds[5] += r1.y; ds[6] += r1.z; ds[7] += r1.w;
            }
        }
        return;
    }

    // kk GEMM: 4 stacked 128x128 tiles per 1024-thread block
    const int b = blockIdx.x - 1;
    const int mg = b >> 3;
    const int nt = b & 7;
    const int w = t >> 6, l = t & 63;
    const int sub = w >> 2;
    const int wsu = w & 3;
    const int wr = wsu >> 1, wc = wsu & 1;
    const int row0 = (mg * 4 + sub) * 128;
    const int col0 = nt * 128;

    floatx4 acc[4][4];
#pragma unroll
    for (int i = 0; i < 4; i++)
#pragma unroll
        for (int j = 0; j < 4; j++) acc[i][j] = (floatx4){0.f, 0.f, 0.f, 0.f};

    int ra0 = row0 + (wsu * 2 + 0) * 16 + (l >> 2); ra0 = ra0 < N_PTS ? ra0 : N_PTS - 1;
    int ra1 = row0 + (wsu * 2 + 1) * 16 + (l >> 2); ra1 = ra1 < N_PTS ? ra1 : N_PTS - 1;
    const long lane_off = (l & 3) * 8;
    const unsigned short* gA0 = X + (long)ra0 * XSTR + lane_off;
    const unsigned short* gA1 = X + (long)ra1 * XSTR + lane_off;
    unsigned short* lA0 = As[sub] + ((wsu * 2 + 0) * 16) * 32;
    unsigned short* lA1 = As[sub] + ((wsu * 2 + 1) * 16) * 32;
    const int rb0 = col0 + (wsu * 2 + 0) * 16 + (l >> 2);
    const int rb1 = col0 + (wsu * 2 + 1) * 16 + (l >> 2);
    const unsigned short* gB0 = Wk_h + (long)rb0 * DIM + lane_off;
    const unsigned short* gB1 = Wk_h + (long)rb1 * DIM + lane_off;
    unsigned short* lB0 = Bs + ((wsu * 2 + 0) * 16) * 32;
    unsigned short* lB1 = Bs + ((wsu * 2 + 1) * 16) * 32;

#pragma unroll 1
    for (int k0 = 0; k0 < DIM; k0 += 32) {
        async_copy16(gA0 + k0, (void*)lA0);
        async_copy16(gA1 + k0, (void*)lA1);
        if (sub == 0) {
            async_copy16(gB0 + k0, (void*)lB0);
            async_copy16(gB1 + k0, (void*)lB1);
        }
        __syncthreads();
        half8 af[4], bfr[4];
#pragma unroll
        for (int ti = 0; ti < 4; ti++)
            af[ti] = *(const half8*)(As[sub] + (wr * 64 + ti * 16 + (l & 15)) * 32 + (l >> 4) * 8);
#pragma unroll
        for (int tj = 0; tj < 4; tj++)
            bfr[tj] = *(const half8*)(Bs + (wc * 64 + tj * 16 + (l & 15)) * 32 + (l >> 4) * 8);
#pragma unroll
        for (int ti = 0; ti < 4; ti++)
#pragma unroll
            for (int tj = 0; tj < 4; tj++)
                acc[ti][tj] = __builtin_amdgcn_mfma_f32_16x16x32_f16(
                    af[ti], bfr[tj], acc[ti][tj], 0, 0, 0);
        __syncthreads();
    }

#pragma unroll
    for (int ti = 0; ti < 4; ti++) {
#pragma unroll
        for (int tj = 0; tj < 4; tj++) {
            const int c = col0 + wc * 64 + tj * 16 + (l & 15);
            const int rbase = row0 + wr * 64 + ti * 16 + (l >> 4) * 4;
            const float bkc = bk[c];
#pragma unroll
            for (int reg = 0; reg < 4; reg++) {
                const int r = rbase + reg;
                if (r < N_PTS)
                    kk_h[(long)r * DIM + c] = f2h(acc[ti][tj][reg] + bkc);
            }
        }
    }
}

// ---------------------------------------------------------------------------
// fp32 SGEMM kept for the small Wv projection only.
// ---------------------------------------------------------------------------
#define BM 128
#define BN 128
#define BKK 8
#define TM 8
#define TN 8

template<bool TRANSB>
__global__ __launch_bounds__(256)
void sgemm_kernel(const float* __restrict__ A, long lda, long az,
                  const float* __restrict__ B, long ldb, long bz,
                  float* __restrict__ C, long ldc, long cz,
                  int M, int N, int Kd,
                  const float* __restrict__ bias, long biasz, float scale)
{
    __shared__ float As[BKK][BM];
    __shared__ float Bs[BKK][BN];
    const int t = threadIdx.x;
    const int z = blockIdx.z;
    A += (long)z * az; B += (long)z * bz; C += (long)z * cz;
    const float* bias_p = bias ? (bias + (long)z * biasz) : nullptr;
    const int row0 = blockIdx.y * BM;
    const int col0 = blockIdx.x * BN;
    const int tx = t & 15, ty = t >> 4;

    float acc[TM][TN];
#pragma unroll
    for (int i = 0; i < TM; i++)
#pragma unroll
        for (int j = 0; j < TN; j++) acc[i][j] = 0.f;

    const int lrow = t >> 1;
    const int lcol = (t & 1) * 4;

    for (int k0 = 0; k0 < Kd; k0 += BKK) {
        {
            int r = row0 + lrow; r = (r < M) ? r : (M - 1);
            float4 v = *(const float4*)(A + (long)r * lda + (k0 + lcol));
            As[lcol + 0][lrow] = v.x; As[lcol + 1][lrow] = v.y;
            As[lcol + 2][lrow] = v.z; As[lcol + 3][lrow] = v.w;
        }
        {
            int r = col0 + lrow; r = (r < N) ? r : (N - 1);
            float4 v = *(const float4*)(B + (long)r * ldb + (k0 + lcol));
            Bs[lcol + 0][lrow] = v.x; Bs[lcol + 1][lrow] = v.y;
            Bs[lcol + 2][lrow] = v.z; Bs[lcol + 3][lrow] = v.w;
        }
        __syncthreads();
#pragma unroll
        for (int kk = 0; kk < BKK; kk++) {
            float a[TM], b[TN];
#pragma unroll
            for (int i = 0; i < TM; i++) a[i] = As[kk][ty * TM + i];
#pragma unroll
            for (int j = 0; j < TN; j++) b[j] = Bs[kk][tx * TN + j];
#pragma unroll
            for (int i = 0; i < TM; i++)
#pragma unroll
                for (int j = 0; j < TN; j++)
                    acc[i][j] = fmaf(a[i], b[j], acc[i][j]);
        }
        __syncthreads();
    }
#pragma unroll
    for (int i = 0; i < TM; i++) {
        int r = row0 + ty * TM + i;
        if (r >= M) continue;
#pragma unroll
        for (int j = 0; j < TN; j++) {
            int c = col0 + tx * TN + j;
            if (c >= N) continue;
            float v = acc[i][j] * scale;
            if (bias_p) v += bias_p[c];
            C[(long)r * ldc + c] = v;
        }
    }
}

// ---------------------------------------------------------------------------
// Fused prep: blocks [0,6000) = sqn + X=[hi|lo] split; [6000,8048) = Wq/Wk conv.
// ---------------------------------------------------------------------------
__global__ __launch_bounds__(256)
void prep_kernel(const float* __restrict__ feat,
                 unsigned short* __restrict__ X, float* __restrict__ sqn,
                 const float* __restrict__ Wq, const float* __restrict__ Wk,
                 unsigned short* __restrict__ Wq_h, unsigned short* __restrict__ Wk_h)
{
    const int t = threadIdx.x;
    if (blockIdx.x < N_PTS) {
        const int r = blockIdx.x;
        float4 v = *(const float4*)(feat + (long)r * DIM + t * 4);
        float s = v.x * v.x + v.y * v.y + v.z * v.z + v.w * v.w;
        ushort4 hi, lo;
        hi.x = f2h(v.x); lo.x = f2h(v.x - h2f(hi.x));
        hi.y = f2h(v.y); lo.y = f2h(v.y - h2f(hi.y));
        hi.z = f2h(v.z); lo.z = f2h(v.z - h2f(hi.z));
        hi.w = f2h(v.w); lo.w = f2h(v.w - h2f(hi.w));
        *(ushort4*)(X + (long)r * XSTR + t * 4) = hi;
        *(ushort4*)(X + (long)r * XSTR + 1024 + t * 4) = lo;
#pragma unroll
        for (int o = 32; o > 0; o >>= 1) s += __shfl_down(s, o);
        __shared__ float sr[4];
        if ((t & 63) == 0) sr[t >> 6] = s;
        __syncthreads();
        if (t == 0) sqn[r] = sr[0] + sr[1] + sr[2] + sr[3];
    } else {
        const int b = blockIdx.x - N_PTS;        // 0..2047
        const float* src = (b < 1024) ? Wq : Wk;
        unsigned short* dst = (b < 1024) ? Wq_h : Wk_h;
        const long i = ((long)(b & 1023) * 256 + t) * 4;
        float4 v = *(const float4*)(src + i);
        ushort4 o;
        o.x = f2h(v.x); o.y = f2h(v.y); o.z = f2h(v.z); o.w = f2h(v.w);
        *(ushort4*)(dst + i) = o;
    }
}

// featT[d][r] = f16(feat[r][d]), 1024 x 6016 (cols 6000..6015 zero)
__global__ __launch_bounds__(256)
void transpose_kernel(const float* __restrict__ feat, unsigned short* __restrict__ featT)
{
    __shared__ unsigned short tile[32][33];
    const int bx = blockIdx.x;
    const int by = blockIdx.y;
    const int t = threadIdx.x;
    const int lr = t >> 3;
    const int lc = (t & 7) * 4;
    const int r = by * 32 + lr;
    if (r < N_PTS) {
        float4 v = *(const float4*)(feat + (long)r * DIM + bx * 32 + lc);
        tile[lr][lc + 0] = f2h(v.x); tile[lr][lc + 1] = f2h(v.y);
        tile[lr][lc + 2] = f2h(v.z); tile[lr][lc + 3] = f2h(v.w);
    } else {
        tile[lr][lc + 0] = 0; tile[lr][lc + 1] = 0;
        tile[lr][lc + 2] = 0; tile[lr][lc + 3] = 0;
    }
    __syncthreads();
    const int orow = bx * 32 + lr;
    ushort4 o;
    o.x = tile[lc + 0][lr]; o.y = tile[lc + 1][lr];
    o.z = tile[lc + 2][lr]; o.w = tile[lc + 3][lr];
    *(ushort4*)(featT + (long)orow * WSTR + by * 32 + lc) = o;
}

// ---------------------------------------------------------------------------
// Gate + logit (R13: transposed LDS coefs, float4 quad reads).
// ---------------------------------------------------------------------------
__global__ __launch_bounds__(256)
void gatelogit_kernel(const float* __restrict__ bboxes,
                      const int* __restrict__ idx,
                      const float* __restrict__ Wg,
                      const float* __restrict__ bgp,
                      float* __restrict__ W)
{
    __shared__ float swgT[64][16];   // swgT[e][g] = Wg[g*64+e]
    __shared__ float sbg[GG];
    __shared__ float sbb[4];
    const int t = threadIdx.x;
    const int k = blockIdx.y;
    const int n = blockIdx.x * 256 + t;
    for (int i = t; i < GG * 64; i += 256) swgT[i & 63][i >> 6] = Wg[i];
    if (t < GG) sbg[t] = bgp[t];
    if (t < 4)  sbb[t] = bboxes[(long)idx[k] * 4 + t];
    __syncthreads();
    if (n >= N_PTS) return;

    const float x1 = sbb[0], y1 = sbb[1], x2 = sbb[2], y2 = sbb[3];
    const float w  = x2 - x1 + 1.f, h = y2 - y1 + 1.f;
    const float cx = 0.5f * (x1 + x2), cy = 0.5f * (y1 + y2);
    float4 rb = *(const float4*)(bboxes + (long)n * 4);
    const float wr = rb.z - rb.x + 1.f, hr = rb.w - rb.y + 1.f;
    const float cxr = 0.5f * (rb.x + rb.z), cyr = 0.5f * (rb.y + rb.w);

    float pos[4];
    pos[0] = __logf(fabsf((cx - cxr) / w) + 1e-3f);
    pos[1] = __logf(fabsf((cy - cyr) / h) + 1e-3f);
    pos[2] = __logf(w / wr);
    pos[3] = __logf(h / hr);

    const float rdm[8] = { 100.0f, 42.169650342858226f, 17.782794100389228f,
                           7.498942093324559f, 3.1622776601683795f,
                           1.333521432163324f, 0.5623413251903491f,
                           0.23713737056616552f };
    float aw[GG];
#pragma unroll
    for (int g = 0; g < GG; g++) aw[g] = sbg[g];
#pragma unroll
    for (int p = 0; p < 4; p++) {
#pragma unroll
        for (int f = 0; f < 8; f++) {
            const float arg = pos[p] * rdm[f];
            const float s_ = __sinf(arg), c_ = __cosf(arg);
            const int e = p * 16 + f;
            const float4* s4 = (const float4*)swgT[e];
            const float4* c4 = (const float4*)swgT[e + 8];
#pragma unroll
            for (int gq = 0; gq < 4; gq++) {
                const float4 sv = s4[gq], cv = c4[gq];
                aw[gq * 4 + 0] += sv.x * s_ + cv.x * c_;
                aw[gq * 4 + 1] += sv.y * s_ + cv.y * c_;
                aw[gq * 4 + 2] += sv.z * s_ + cv.z * c_;
                aw[gq * 4 + 3] += sv.w * s_ + cv.w * c_;
            }
        }
    }
    float* base = W + ((long)k * GG) * WSTR + n;
#pragma unroll
    for (int g = 0; g < GG; g++) {
        const float lg = __logf(fmaxf(aw[g], 0.f) + 1e-6f);
        base[(long)g * WSTR] += lg;
    }
}

// ---------------------------------------------------------------------------
// Softmax over n, one block per (k,g) row; in-place fp32 -> f16.
// ---------------------------------------------------------------------------
__global__ __launch_bounds__(256)
void softmax16_kernel(float* __restrict__ W)
{
    __shared__ float lg[WSTR];
    __shared__ float sred[4];
    __shared__ float sMS;
    const int t = threadIdx.x;
    float* rowp = W + (long)blockIdx.x * WSTR;

    float m = -INFINITY;
    for (int n = t; n < N_PTS; n += 256) {
        const float v = rowp[n];
        lg[n] = v;
        m = fmaxf(m, v);
    }
#pragma unroll
    for (int o = 32; o > 0; o >>= 1) m = fmaxf(m, __shfl_down(m, o));
    if ((t & 63) == 0) sred[t >> 6] = m;
    __syncthreads();
    if (t == 0) sMS = fmaxf(fmaxf(sred[0], sred[1]), fmaxf(sred[2], sred[3]));
    __syncthreads();
    m = sMS;
    __syncthreads();

    float s = 0.f;
    for (int n = t; n < N_PTS; n += 256) {
        const float e = __expf(lg[n] - m);
        lg[n] = e;
        s += e;
    }
#pragma unroll
    for (int o = 32; o > 0; o >>= 1) s += __shfl_down(s, o);
    if ((t & 63) == 0) sred[t >> 6] = s;
    __syncthreads();
    if (t == 0) sMS = sred[0] + sred[1] + sred[2] + sred[3];
    __syncthreads();
    const float inv = 1.0f / sMS;
    __syncthreads();

    unsigned short* orow = (unsigned short*)rowp;
    for (int n = t; n < WSTR; n += 256)
        orow[n] = (n < N_PTS) ? f2h(lg[n] * inv) : (unsigned short)0;
}

// out_t reduce: a += b (split-K partials), float4
__global__ __launch_bounds__(256)
void addbuf_kernel(float* __restrict__ a, const float* __restrict__ b)
{
    const long i = ((long)blockIdx.x * 256 + threadIdx.x) * 4;
    float4 va = *(const float4*)(a + i);
    float4 vb = *(const float4*)(b + i);
    va.x += vb.x; va.y += vb.y; va.z += vb.z; va.w += vb.w;
    *(float4*)(a + i) = va;
}

// ---------------------------------------------------------------------------
extern "C" void kernel_launch(void* const* d_in, const int* in_sizes, int n_in,
                              void* d_out, int out_size, void* d_ws, size_t ws_size,
                              hipStream_t stream)
{
    const float* feat   = (const float*)d_in[0];
    const float* bboxes = (const float*)d_in[1];
    const float* Wq     = (const float*)d_in[2];
    const float* bq     = (const float*)d_in[3];
    const float* Wk     = (const float*)d_in[4];
    const float* bk     = (const float*)d_in[5];
    const float* Wg     = (const float*)d_in[6];
    const float* bg     = (const float*)d_in[7];
    const float* Wv     = (const float*)d_in[8];
    const float* bv     = (const float*)d_in[9];
    float* out = (float*)d_out;
    float* ws  = (float*)d_ws;

    // ws layout (float offsets), peak ~186.7 MB (<= 190.72 MB known-safe):
    //  drec  [0, 36,000,000)   dead after FPS; then:
    //    W probs [0, 28,876,800)    fp32 logits -> f16 in place
    //    featT   [28,900,000, 31,980,192)   1024x6016 f16 (post-FPS)
    //    outt    [32,000,000, 36,915,200)   out_t partial z=0 (X dead by then)
    //    outt2   [37,000,000, 41,915,200)   out_t partial z=1
    //  X     [36,000,000, 42,144,000)  [hi|lo] f16; dead after q-gather
    //  kk_h  [42,200,000, 45,272,000)  f16 (written DURING fps)
    //  q_h   [45,280,000, 45,433,600)
    //  Wq_h  [45,600,000, 46,124,288)
    //  Wk_h  [46,130,000, 46,654,288)
    //  sqn   [46,660,000, 46,666,000)
    //  idx   [46,666,000, ...)
    float* drec = ws;
    float* W    = ws;
    unsigned short* featT = (unsigned short*)(ws + 28900000);
    float* outt           = ws + 32000000;
    float* outt2          = ws + 37000000;
    unsigned short* X     = (unsigned short*)(ws + 36000000);
    unsigned short* kk_h  = (unsigned short*)(ws + 42200000);
    unsigned short* q_h   = (unsigned short*)(ws + 45280000);
    unsigned short* Wq_h  = (unsigned short*)(ws + 45600000);
    unsigned short* Wk_h  = (unsigned short*)(ws + 46130000);
    float* sqnbuf         = ws + 46660000;
    int*   idxbuf         = (int*)(ws + 46666000);
    if (ws_size < (size_t)186700000) return;

    // prep: sqn + X split + Wq/Wk f16 conversion, one launch
    prep_kernel<<<N_PTS + 2048, 256, 0, stream>>>(
        feat, X, sqnbuf, Wq, Wk, Wq_h, Wk_h);

    // Gram: fused-K (Ahi/Alo/Bhi/Blo staged once, 3 combos per barrier)
    gram_kernel<<<1128, 256, 0, stream>>>(X, drec, sqnbuf, 47);

    // FAT: block 0 = fps (single-barrier reduction); blocks 1..96 = kk GEMM
    fps_kk_kernel<<<97, 1024, 0, stream>>>(drec, idxbuf, X, Wk_h, bk, kk_h);

    transpose_kernel<<<dim3(32, 188), 256, 0, stream>>>(feat, featT);

    // q = X[idx] @ Wq^T + bq  (A gathered via idx; f16 out)
    mfma_gemm<true><<<dim3(8, 3, 1), 256, 0, stream>>>(
        X, XSTR, 0, Wq_h, 1024, 0, q_h, 1024, 0,
        KSEL, DIM, DIM, bq, 0, 1.f, idxbuf);

    // aff = (q . kk^T)/8 per group -> W fp32  (batched z=16, K=64)
    mfma_gemm<false><<<dim3(47, 3, GG), 256, 0, stream>>>(
        q_h, 1024, 64, kk_h, 1024, 64, W, (long)GG * WSTR, WSTR,
        KSEL, N_PTS, 64, nullptr, 0, 0.125f, nullptr);

    // gate + logit, then softmax (f16 probs in place)
    gatelogit_kernel<<<dim3(24, KSEL), 256, 0, stream>>>(
        bboxes, idxbuf, Wg, bg, W);
    softmax16_kernel<<<KSEL * GG, 256, 0, stream>>>(W);

    // out_t = P @ feat, split-K x2 via z (az=bz=3008), partials -> add
    mfma_gemm<false><<<dim3(8, 38, 2), 256, 0, stream>>>(
        (unsigned short*)W, 2 * WSTR, 3008, featT, WSTR, 3008,
        outt, DIM, 5000000,
        KSEL * GG, DIM, 3008, nullptr, 0, 1.f, nullptr);
    addbuf_kernel<<<4800, 256, 0, stream>>>(outt, outt2);

    // out = out_t . Wv + bv (fp32, small)
    sgemm_kernel<true><<<dim3(1, 3, GG), 256, 0, stream>>>(
        outt, (long)GG * DIM, DIM, Wv, DIM, (long)DGR * DIM, out, DIM, DGR,
        KSEL, DGR, DIM, bv, DGR, 1.f);
}